// Round 4
// baseline (1764.151 us; speedup 1.0000x reference)
//
#include <hip/hip_runtime.h>
#include <hip/hip_bf16.h>

// CxNNxNN attention. B=8, C=64, H=W=256, head=8, N=8.
// token n = (h&7)*8 + (w&7)  [64], feature d = (h>>3)*32 + (w>>3)  [1024].

#define LSTR 68  // LDS row stride (floats); 68 => <=2-way bank aliasing

// ---------------- K1/K3: pointwise GEMM  out[oc] = sum_c w[oc,c] * in[c] ----
// R1/R3 failure: any scheme where one thread holds x[64] across a sequential
// oc loop spills (compiler re-loads or scratch-spills; 845MB fetch). Fix:
// split oc across the block's 4 wave-quarters (q owns oc [q*OC/4, ...)).
// x tile = 16KB LDS (64 px x 64 ch), read from HBM exactly once; per-thread
// state is only acc[OC/4]. 8 blocks/CU occupancy (vs R2's 64KB-LDS 2/CU).
// LDS reads xl[c][p]: c uniform, p=lane -> stride-1 conflict-free.
// Weight reads wave-uniform -> s_load. In-place proj (in==outp) safe: all
// reads land in LDS before the barrier; blocks touch disjoint pixels.
template <int OC>
__global__ __launch_bounds__(256) void k_pw(const float* in,
                                            const float* __restrict__ w,
                                            float* outp) {
  constexpr int PEROC = OC / 4;  // 48 (qkv) or 16 (proj)
  __shared__ float xl[64][64];
  const int t = threadIdx.x;
  const int p = t & 63, q = t >> 6;  // pixel lane, oc-quarter
  const size_t pix0 = (size_t)blockIdx.x * 64;
  const int b = (int)(pix0 >> 16);
  const int hw0 = (int)(pix0 & 65535);
  const float* ib = in + (((size_t)b * 64) << 16) + hw0 + p;
#pragma unroll
  for (int r = 0; r < 16; ++r) {
    int c = r * 4 + q;
    xl[c][p] = ib[(size_t)c << 16];
  }
  __syncthreads();
  const int oc0 = q * PEROC;
  float acc[PEROC];
#pragma unroll
  for (int j = 0; j < PEROC; ++j) acc[j] = 0.f;
#pragma unroll 4
  for (int c = 0; c < 64; ++c) {
    const float xv = xl[c][p];
#pragma unroll
    for (int j = 0; j < PEROC; ++j)
      acc[j] = fmaf(w[(oc0 + j) * 64 + c], xv, acc[j]);  // uniform -> s_load
  }
  float* ob = outp + (((size_t)b * OC) << 16) + hw0 + p;
#pragma unroll
  for (int j = 0; j < PEROC; ++j) ob[(size_t)(oc0 + j) << 16] = acc[j];
}

// ---- fused depthwise-3x3 conv + permuted staging into LDS [64 n][64 dcol] ----
// chunk cd covers d in [cd*64, cd*64+64)  <=> image rows h in [cd*16, cd*16+16)
__device__ __forceinline__ void stage_conv(const float* __restrict__ pl,
                                           const float* __restrict__ w9,
                                           float* __restrict__ lds, int cd,
                                           int t) {
#pragma unroll
  for (int rr = 0; rr < 2; ++rr) {
    int r = t + rr * 256;          // 512 runs: 16 rows x 32 w-tiles
    int lr = r >> 5, w0 = r & 31;  // local row, w-tile (8 px)
    int h = cd * 16 + lr;
    float rv[3][10];
#pragma unroll
    for (int dy = 0; dy < 3; ++dy) {
      int hy = h + dy - 1;
      bool hv = (hy >= 0) && (hy < 256);
#pragma unroll
      for (int j = 0; j < 10; ++j) rv[dy][j] = 0.f;
      if (hv) {
        const float* rp = pl + hy * 256;
        const float4* rp4 = (const float4*)(rp + w0 * 8);
        float4 a = rp4[0], b4 = rp4[1];
        rv[dy][1] = a.x;  rv[dy][2] = a.y;  rv[dy][3] = a.z;  rv[dy][4] = a.w;
        rv[dy][5] = b4.x; rv[dy][6] = b4.y; rv[dy][7] = b4.z; rv[dy][8] = b4.w;
        rv[dy][0] = (w0 > 0) ? rp[w0 * 8 - 1] : 0.f;   // left halo / zero pad
        rv[dy][9] = (w0 < 31) ? rp[w0 * 8 + 8] : 0.f;  // right halo / zero pad
      }
    }
    int nb = (lr & 7) * 8;               // n base (nh*8), i -> nw
    int dcol = ((lr >> 3) << 5) + w0;    // local d column
#pragma unroll
    for (int i = 0; i < 8; ++i) {
      float o = fmaf(w9[0], rv[0][i], fmaf(w9[1], rv[0][i + 1], fmaf(w9[2], rv[0][i + 2],
                fmaf(w9[3], rv[1][i], fmaf(w9[4], rv[1][i + 1], fmaf(w9[5], rv[1][i + 2],
                fmaf(w9[6], rv[2][i], fmaf(w9[7], rv[2][i + 1], w9[8] * rv[2][i + 2]))))))));
      lds[(nb + i) * LSTR + dcol] = o;
    }
  }
}

// ---------------- K2: per-(b,ch) attention, conv fused in staging -------------
__global__ __launch_bounds__(256) void k_attn(
    const float* __restrict__ qkv0, const float* __restrict__ wdw,
    const float* __restrict__ temperature, float* __restrict__ out) {
  __shared__ float bufA[64 * LSTR];  // Q chunks, then P^T
  __shared__ float bufB[64 * LSTR];  // K chunks, then V chunks
  __shared__ float red[64 * 8];
  __shared__ float invn[128];

  const int t = threadIdx.x;
  const int b = blockIdx.x >> 6, ch = blockIdx.x & 63;
  const float* qpl = qkv0 + (((size_t)b * 192 + ch) << 16);
  const float* kpl = qkv0 + (((size_t)b * 192 + 64 + ch) << 16);
  const float* vpl = qkv0 + (((size_t)b * 192 + 128 + ch) << 16);
  float wq[9], wk[9], wv[9];
#pragma unroll
  for (int i = 0; i < 9; ++i) {  // uniform indices -> scalar regs
    wq[i] = wdw[ch * 9 + i];
    wk[i] = wdw[(64 + ch) * 9 + i];
    wv[i] = wdw[(128 + ch) * 9 + i];
  }
  const float tscale = temperature[ch >> 3];

  const int tn = t >> 4, tmw = t & 15;  // S tile: rows tn*4+i, cols tmw+16*j
  float s_acc[4][4];
#pragma unroll
  for (int i = 0; i < 4; ++i)
#pragma unroll
    for (int j = 0; j < 4; ++j) s_acc[i][j] = 0.f;
  float sqQ = 0.f, sqK = 0.f;

  for (int cd = 0; cd < 16; ++cd) {
    stage_conv(qpl, wq, bufA, cd, t);
    stage_conv(kpl, wk, bufB, cd, t);
    __syncthreads();
    {  // sumsq partials: row n = t>>2, 16 cols
      int n = t >> 2, d0 = (t & 3) << 4;
#pragma unroll
      for (int k4 = 0; k4 < 4; ++k4) {
        float4 qv = *(const float4*)&bufA[n * LSTR + d0 + k4 * 4];
        float4 kv = *(const float4*)&bufB[n * LSTR + d0 + k4 * 4];
        sqQ += qv.x * qv.x + qv.y * qv.y + qv.z * qv.z + qv.w * qv.w;
        sqK += kv.x * kv.x + kv.y * kv.y + kv.z * kv.z + kv.w * kv.w;
      }
    }
#pragma unroll 2
    for (int ds = 0; ds < 16; ++ds) {
      float qv[4][4], kv[4][4];
#pragma unroll
      for (int i = 0; i < 4; ++i) {
        float4 v4 = *(const float4*)&bufA[(tn * 4 + i) * LSTR + ds * 4];
        qv[i][0] = v4.x; qv[i][1] = v4.y; qv[i][2] = v4.z; qv[i][3] = v4.w;
      }
#pragma unroll
      for (int j = 0; j < 4; ++j) {
        float4 v4 = *(const float4*)&bufB[(tmw + 16 * j) * LSTR + ds * 4];
        kv[j][0] = v4.x; kv[j][1] = v4.y; kv[j][2] = v4.z; kv[j][3] = v4.w;
      }
#pragma unroll
      for (int i = 0; i < 4; ++i)
#pragma unroll
        for (int j = 0; j < 4; ++j) {
          float s = s_acc[i][j];
          s = fmaf(qv[i][0], kv[j][0], s);
          s = fmaf(qv[i][1], kv[j][1], s);
          s = fmaf(qv[i][2], kv[j][2], s);
          s = fmaf(qv[i][3], kv[j][3], s);
          s_acc[i][j] = s;
        }
    }
    __syncthreads();
  }

  // reduce sumsq -> 1/max(||.||, 1e-12)
  red[(t >> 2) * 8 + (t & 3)] = sqQ;
  red[(t >> 2) * 8 + 4 + (t & 3)] = sqK;
  __syncthreads();
  if (t < 128) {
    int n = t & 63;
    int o = (t >> 6) * 4;
    float s = red[n * 8 + o] + red[n * 8 + o + 1] + red[n * 8 + o + 2] +
              red[n * 8 + o + 3];
    invn[(t >> 6) * 64 + n] = 1.f / fmaxf(sqrtf(s), 1e-12f);
  }
  __syncthreads();

  // scale + softmax over m (16-lane shfl groups)
  float iq[4], ik[4];
#pragma unroll
  for (int i = 0; i < 4; ++i) iq[i] = invn[tn * 4 + i];
#pragma unroll
  for (int j = 0; j < 4; ++j) ik[j] = invn[64 + tmw + 16 * j];
#pragma unroll
  for (int i = 0; i < 4; ++i) {
#pragma unroll
    for (int j = 0; j < 4; ++j) s_acc[i][j] *= iq[i] * ik[j] * tscale;
    float m = fmaxf(fmaxf(s_acc[i][0], s_acc[i][1]),
                    fmaxf(s_acc[i][2], s_acc[i][3]));
#pragma unroll
    for (int off = 1; off < 16; off <<= 1) m = fmaxf(m, __shfl_xor(m, off));
    float ssum = 0.f;
#pragma unroll
    for (int j = 0; j < 4; ++j) {
      s_acc[i][j] = __expf(s_acc[i][j] - m);
      ssum += s_acc[i][j];
    }
#pragma unroll
    for (int off = 1; off < 16; off <<= 1) ssum += __shfl_xor(ssum, off);
    float rs = 1.f / ssum;
#pragma unroll
    for (int j = 0; j < 4; ++j) s_acc[i][j] *= rs;
  }

  // write P^T into bufA (phase-1 reads of bufA all completed before red barrier)
#pragma unroll
  for (int j = 0; j < 4; ++j) {
    float4 c4 = make_float4(s_acc[0][j], s_acc[1][j], s_acc[2][j], s_acc[3][j]);
    *(float4*)&bufA[(tmw + 16 * j) * LSTR + tn * 4] = c4;
  }
  __syncthreads();

  // phase 3: O = P V, stream conv'd V chunks; write raster into out
  const int td = tmw;
  size_t obase = ((size_t)b * 64 + ch) << 16;
  for (int cd = 0; cd < 16; ++cd) {
    stage_conv(vpl, wv, bufB, cd, t);
    __syncthreads();
    float oa[4][4];
#pragma unroll
    for (int i = 0; i < 4; ++i)
#pragma unroll
      for (int j = 0; j < 4; ++j) oa[i][j] = 0.f;
#pragma unroll 2
    for (int m = 0; m < 64; ++m) {
      float4 p4 = *(const float4*)&bufA[m * LSTR + tn * 4];
      float4 v4 = *(const float4*)&bufB[m * LSTR + td * 4];
      float pv[4] = {p4.x, p4.y, p4.z, p4.w};
      float vv[4] = {v4.x, v4.y, v4.z, v4.w};
#pragma unroll
      for (int i = 0; i < 4; ++i)
#pragma unroll
        for (int j = 0; j < 4; ++j) oa[i][j] = fmaf(pv[i], vv[j], oa[i][j]);
    }
#pragma unroll
    for (int i = 0; i < 4; ++i) {
      int n = tn * 4 + i;
      int hb = n >> 3, wb = n & 7;
#pragma unroll
      for (int j = 0; j < 4; ++j) {
        int d = cd * 64 + td * 4 + j;
        int h = ((d >> 5) << 3) + hb;
        int w = ((d & 31) << 3) + wb;
        out[obase + h * 256 + w] = oa[i][j];
      }
    }
    __syncthreads();
  }
}

extern "C" void kernel_launch(void* const* d_in, const int* in_sizes, int n_in,
                              void* d_out, int out_size, void* d_ws,
                              size_t ws_size, hipStream_t stream) {
  const float* x = (const float*)d_in[0];
  const float* wqkv = (const float*)d_in[1];
  const float* wdw = (const float*)d_in[2];
  const float* wproj = (const float*)d_in[3];
  const float* temp = (const float*)d_in[4];
  float* out = (float*)d_out;
  float* qkv0 = (float*)d_ws;  // 8*192*65536*4 = 402,653,184 bytes

  k_pw<192><<<8192, 256, 0, stream>>>(x, wqkv, qkv0);
  k_attn<<<512, 256, 0, stream>>>(qkv0, wdw, temp, out);
  k_pw<64><<<8192, 256, 0, stream>>>(out, wproj, out);
}

// Round 5
// 565.662 us; speedup vs baseline: 3.1187x; 3.1187x over previous
//
#include <hip/hip_runtime.h>
#include <hip/hip_bf16.h>

// CxNNxNN attention. B=8, C=64, H=W=256, head=8, N=8.
// token n = (h&7)*8 + (w&7)  [64], feature d = (h>>3)*32 + (w>>3)  [1024].

#define LSTR 68  // LDS row stride (floats); 68 => <=2-way bank aliasing

// ---------------- K1/K3: pointwise GEMM  out[oc] = sum_c w[oc,c] * in[c] ----
// Lessons R1-R4: need simultaneously (a) x staged once (small LDS tile, not
// VGPRs -- allocator re-loads/spills any 64-deep live array), (b) weight
// address wave-uniform in the compiler's divergence analysis -> s_load
// (R4: t>>6-derived index => per-lane global_load, VGPR=196, 12% occ),
// (c) per-thread state = acc[16] only. Block = 64 pixels x 256 threads;
// 4 wave-quarters own disjoint oc ranges; quarter index via readfirstlane;
// each quarter loops sub-groups of 16 ocs re-reading x from LDS (cheap).
// In-place proj safe: all reads in LDS before barrier; disjoint pixels/block.
template <int OC>
__global__ __launch_bounds__(256) void k_pw(const float* in,
                                            const float* __restrict__ w,
                                            float* outp) {
  constexpr int PEROC = OC / 4;   // 48 (qkv) or 16 (proj)
  constexpr int NG = PEROC / 16;  // 3 or 1 sub-groups of 16
  __shared__ float xl[64][64];    // 16KB
  const int t = threadIdx.x;
  const int p = t & 63;                                  // pixel lane
  const int qw = __builtin_amdgcn_readfirstlane(t >> 6); // oc-quarter, SGPR
  const size_t pix0 = (size_t)blockIdx.x * 64;
  const int b = (int)(pix0 >> 16);
  const int hw0 = (int)(pix0 & 65535);
  const float* ib = in + (((size_t)b * 64) << 16) + hw0 + p;
#pragma unroll
  for (int r = 0; r < 16; ++r) {
    int c = r * 4 + (t >> 6);
    xl[c][p] = ib[(size_t)c << 16];  // wave: 256B coalesced
  }
  __syncthreads();
  float* ob = outp + (((size_t)b * OC) << 16) + hw0 + p;
#pragma unroll 1
  for (int g = 0; g < NG; ++g) {
    const float* wg = w + (qw * PEROC + g * 16) * 64;  // SGPR-uniform base
    float acc[16];
#pragma unroll
    for (int j = 0; j < 16; ++j) acc[j] = 0.f;
#pragma unroll 4
    for (int c = 0; c < 64; ++c) {
      const float xv = xl[c][p];  // lanes stride-1 -> 2-way bank (free)
#pragma unroll
      for (int j = 0; j < 16; ++j)
        acc[j] = fmaf(wg[j * 64 + c], xv, acc[j]);  // uniform -> s_load
    }
#pragma unroll
    for (int j = 0; j < 16; ++j)
      ob[(size_t)(qw * PEROC + g * 16 + j) << 16] = acc[j];
  }
}

// ---- fused depthwise-3x3 conv + permuted staging into LDS [64 n][64 dcol] ----
// chunk cd covers d in [cd*64, cd*64+64)  <=> image rows h in [cd*16, cd*16+16)
__device__ __forceinline__ void stage_conv(const float* __restrict__ pl,
                                           const float* __restrict__ w9,
                                           float* __restrict__ lds, int cd,
                                           int t) {
#pragma unroll
  for (int rr = 0; rr < 2; ++rr) {
    int r = t + rr * 256;          // 512 runs: 16 rows x 32 w-tiles
    int lr = r >> 5, w0 = r & 31;  // local row, w-tile (8 px)
    int h = cd * 16 + lr;
    float rv[3][10];
#pragma unroll
    for (int dy = 0; dy < 3; ++dy) {
      int hy = h + dy - 1;
      bool hv = (hy >= 0) && (hy < 256);
#pragma unroll
      for (int j = 0; j < 10; ++j) rv[dy][j] = 0.f;
      if (hv) {
        const float* rp = pl + hy * 256;
        const float4* rp4 = (const float4*)(rp + w0 * 8);
        float4 a = rp4[0], b4 = rp4[1];
        rv[dy][1] = a.x;  rv[dy][2] = a.y;  rv[dy][3] = a.z;  rv[dy][4] = a.w;
        rv[dy][5] = b4.x; rv[dy][6] = b4.y; rv[dy][7] = b4.z; rv[dy][8] = b4.w;
        rv[dy][0] = (w0 > 0) ? rp[w0 * 8 - 1] : 0.f;   // left halo / zero pad
        rv[dy][9] = (w0 < 31) ? rp[w0 * 8 + 8] : 0.f;  // right halo / zero pad
      }
    }
    int nb = (lr & 7) * 8;               // n base (nh*8), i -> nw
    int dcol = ((lr >> 3) << 5) + w0;    // local d column
#pragma unroll
    for (int i = 0; i < 8; ++i) {
      float o = fmaf(w9[0], rv[0][i], fmaf(w9[1], rv[0][i + 1], fmaf(w9[2], rv[0][i + 2],
                fmaf(w9[3], rv[1][i], fmaf(w9[4], rv[1][i + 1], fmaf(w9[5], rv[1][i + 2],
                fmaf(w9[6], rv[2][i], fmaf(w9[7], rv[2][i + 1], w9[8] * rv[2][i + 2]))))))));
      lds[(nb + i) * LSTR + dcol] = o;
    }
  }
}

// ---------------- K2: per-(b,ch) attention, conv fused in staging -------------
__global__ __launch_bounds__(256) void k_attn(
    const float* __restrict__ qkv0, const float* __restrict__ wdw,
    const float* __restrict__ temperature, float* __restrict__ out) {
  __shared__ float bufA[64 * LSTR];  // Q chunks, then P^T
  __shared__ float bufB[64 * LSTR];  // K chunks, then V chunks
  __shared__ float red[64 * 8];
  __shared__ float invn[128];

  const int t = threadIdx.x;
  const int b = blockIdx.x >> 6, ch = blockIdx.x & 63;
  const float* qpl = qkv0 + (((size_t)b * 192 + ch) << 16);
  const float* kpl = qkv0 + (((size_t)b * 192 + 64 + ch) << 16);
  const float* vpl = qkv0 + (((size_t)b * 192 + 128 + ch) << 16);
  float wq[9], wk[9], wv[9];
#pragma unroll
  for (int i = 0; i < 9; ++i) {  // uniform indices -> scalar regs
    wq[i] = wdw[ch * 9 + i];
    wk[i] = wdw[(64 + ch) * 9 + i];
    wv[i] = wdw[(128 + ch) * 9 + i];
  }
  const float tscale = temperature[ch >> 3];

  const int tn = t >> 4, tmw = t & 15;  // S tile: rows tn*4+i, cols tmw+16*j
  float s_acc[4][4];
#pragma unroll
  for (int i = 0; i < 4; ++i)
#pragma unroll
    for (int j = 0; j < 4; ++j) s_acc[i][j] = 0.f;
  float sqQ = 0.f, sqK = 0.f;

  for (int cd = 0; cd < 16; ++cd) {
    stage_conv(qpl, wq, bufA, cd, t);
    stage_conv(kpl, wk, bufB, cd, t);
    __syncthreads();
    {  // sumsq partials: row n = t>>2, 16 cols
      int n = t >> 2, d0 = (t & 3) << 4;
#pragma unroll
      for (int k4 = 0; k4 < 4; ++k4) {
        float4 qv = *(const float4*)&bufA[n * LSTR + d0 + k4 * 4];
        float4 kv = *(const float4*)&bufB[n * LSTR + d0 + k4 * 4];
        sqQ += qv.x * qv.x + qv.y * qv.y + qv.z * qv.z + qv.w * qv.w;
        sqK += kv.x * kv.x + kv.y * kv.y + kv.z * kv.z + kv.w * kv.w;
      }
    }
#pragma unroll 2
    for (int ds = 0; ds < 16; ++ds) {
      float qv[4][4], kv[4][4];
#pragma unroll
      for (int i = 0; i < 4; ++i) {
        float4 v4 = *(const float4*)&bufA[(tn * 4 + i) * LSTR + ds * 4];
        qv[i][0] = v4.x; qv[i][1] = v4.y; qv[i][2] = v4.z; qv[i][3] = v4.w;
      }
#pragma unroll
      for (int j = 0; j < 4; ++j) {
        float4 v4 = *(const float4*)&bufB[(tmw + 16 * j) * LSTR + ds * 4];
        kv[j][0] = v4.x; kv[j][1] = v4.y; kv[j][2] = v4.z; kv[j][3] = v4.w;
      }
#pragma unroll
      for (int i = 0; i < 4; ++i)
#pragma unroll
        for (int j = 0; j < 4; ++j) {
          float s = s_acc[i][j];
          s = fmaf(qv[i][0], kv[j][0], s);
          s = fmaf(qv[i][1], kv[j][1], s);
          s = fmaf(qv[i][2], kv[j][2], s);
          s = fmaf(qv[i][3], kv[j][3], s);
          s_acc[i][j] = s;
        }
    }
    __syncthreads();
  }

  // reduce sumsq -> 1/max(||.||, 1e-12)
  red[(t >> 2) * 8 + (t & 3)] = sqQ;
  red[(t >> 2) * 8 + 4 + (t & 3)] = sqK;
  __syncthreads();
  if (t < 128) {
    int n = t & 63;
    int o = (t >> 6) * 4;
    float s = red[n * 8 + o] + red[n * 8 + o + 1] + red[n * 8 + o + 2] +
              red[n * 8 + o + 3];
    invn[(t >> 6) * 64 + n] = 1.f / fmaxf(sqrtf(s), 1e-12f);
  }
  __syncthreads();

  // scale + softmax over m (16-lane shfl groups)
  float iq[4], ik[4];
#pragma unroll
  for (int i = 0; i < 4; ++i) iq[i] = invn[tn * 4 + i];
#pragma unroll
  for (int j = 0; j < 4; ++j) ik[j] = invn[64 + tmw + 16 * j];
#pragma unroll
  for (int i = 0; i < 4; ++i) {
#pragma unroll
    for (int j = 0; j < 4; ++j) s_acc[i][j] *= iq[i] * ik[j] * tscale;
    float m = fmaxf(fmaxf(s_acc[i][0], s_acc[i][1]),
                    fmaxf(s_acc[i][2], s_acc[i][3]));
#pragma unroll
    for (int off = 1; off < 16; off <<= 1) m = fmaxf(m, __shfl_xor(m, off));
    float ssum = 0.f;
#pragma unroll
    for (int j = 0; j < 4; ++j) {
      s_acc[i][j] = __expf(s_acc[i][j] - m);
      ssum += s_acc[i][j];
    }
#pragma unroll
    for (int off = 1; off < 16; off <<= 1) ssum += __shfl_xor(ssum, off);
    float rs = 1.f / ssum;
#pragma unroll
    for (int j = 0; j < 4; ++j) s_acc[i][j] *= rs;
  }

  // write P^T into bufA (phase-1 reads of bufA all completed before red barrier)
#pragma unroll
  for (int j = 0; j < 4; ++j) {
    float4 c4 = make_float4(s_acc[0][j], s_acc[1][j], s_acc[2][j], s_acc[3][j]);
    *(float4*)&bufA[(tmw + 16 * j) * LSTR + tn * 4] = c4;
  }
  __syncthreads();

  // phase 3: O = P V, stream conv'd V chunks; write raster into out
  const int td = tmw;
  size_t obase = ((size_t)b * 64 + ch) << 16;
  for (int cd = 0; cd < 16; ++cd) {
    stage_conv(vpl, wv, bufB, cd, t);
    __syncthreads();
    float oa[4][4];
#pragma unroll
    for (int i = 0; i < 4; ++i)
#pragma unroll
      for (int j = 0; j < 4; ++j) oa[i][j] = 0.f;
#pragma unroll 2
    for (int m = 0; m < 64; ++m) {
      float4 p4 = *(const float4*)&bufA[m * LSTR + tn * 4];
      float4 v4 = *(const float4*)&bufB[m * LSTR + td * 4];
      float pv[4] = {p4.x, p4.y, p4.z, p4.w};
      float vv[4] = {v4.x, v4.y, v4.z, v4.w};
#pragma unroll
      for (int i = 0; i < 4; ++i)
#pragma unroll
        for (int j = 0; j < 4; ++j) oa[i][j] = fmaf(pv[i], vv[j], oa[i][j]);
    }
#pragma unroll
    for (int i = 0; i < 4; ++i) {
      int n = tn * 4 + i;
      int hb = n >> 3, wb = n & 7;
#pragma unroll
      for (int j = 0; j < 4; ++j) {
        int d = cd * 64 + td * 4 + j;
        int h = ((d >> 5) << 3) + hb;
        int w = ((d & 31) << 3) + wb;
        out[obase + h * 256 + w] = oa[i][j];
      }
    }
    __syncthreads();
  }
}

extern "C" void kernel_launch(void* const* d_in, const int* in_sizes, int n_in,
                              void* d_out, int out_size, void* d_ws,
                              size_t ws_size, hipStream_t stream) {
  const float* x = (const float*)d_in[0];
  const float* wqkv = (const float*)d_in[1];
  const float* wdw = (const float*)d_in[2];
  const float* wproj = (const float*)d_in[3];
  const float* temp = (const float*)d_in[4];
  float* out = (float*)d_out;
  float* qkv0 = (float*)d_ws;  // 8*192*65536*4 = 402,653,184 bytes

  k_pw<192><<<8192, 256, 0, stream>>>(x, wqkv, qkv0);
  k_attn<<<512, 256, 0, stream>>>(qkv0, wdw, temp, out);
  k_pw<64><<<8192, 256, 0, stream>>>(out, wproj, out);
}

// Round 6
// 511.725 us; speedup vs baseline: 3.4475x; 1.1054x over previous
//
#include <hip/hip_runtime.h>
#include <hip/hip_bf16.h>

// CxNNxNN attention. B=8, C=64, H=W=256, head=8, N=8.
// token n = (h&7)*8 + (w&7)  [64], feature d = (h>>3)*32 + (w>>3)  [1024].

typedef __attribute__((ext_vector_type(8))) short short8;  // 8 bf16 (4 VGPR)
typedef __attribute__((ext_vector_type(4))) float f4;      // MFMA acc
typedef unsigned short u16;

#define PST 72  // bf16 plane row stride (ushorts); 144B rows, 16B-aligned frags

// ---------------- K1/K3: pointwise GEMM (unchanged from R5) ----------------
template <int OC>
__global__ __launch_bounds__(256) void k_pw(const float* in,
                                            const float* __restrict__ w,
                                            float* outp) {
  constexpr int PEROC = OC / 4;
  constexpr int NG = PEROC / 16;
  __shared__ float xl[64][64];
  const int t = threadIdx.x;
  const int p = t & 63;
  const int qw = __builtin_amdgcn_readfirstlane(t >> 6);
  const size_t pix0 = (size_t)blockIdx.x * 64;
  const int b = (int)(pix0 >> 16);
  const int hw0 = (int)(pix0 & 65535);
  const float* ib = in + (((size_t)b * 64) << 16) + hw0 + p;
#pragma unroll
  for (int r = 0; r < 16; ++r) {
    int c = r * 4 + (t >> 6);
    xl[c][p] = ib[(size_t)c << 16];
  }
  __syncthreads();
  float* ob = outp + (((size_t)b * OC) << 16) + hw0 + p;
#pragma unroll 1
  for (int g = 0; g < NG; ++g) {
    const float* wg = w + (qw * PEROC + g * 16) * 64;
    float acc[16];
#pragma unroll
    for (int j = 0; j < 16; ++j) acc[j] = 0.f;
#pragma unroll 4
    for (int c = 0; c < 64; ++c) {
      const float xv = xl[c][p];
#pragma unroll
      for (int j = 0; j < 16; ++j)
        acc[j] = fmaf(wg[j * 64 + c], xv, acc[j]);
    }
#pragma unroll
    for (int j = 0; j < 16; ++j)
      ob[(size_t)(qw * PEROC + g * 16 + j) << 16] = acc[j];
  }
}

// ---------------- bf16 hi/lo helpers ----------------
__device__ __forceinline__ float tof(u16 u) {
  return __builtin_bit_cast(float, ((unsigned)u) << 16);
}
__device__ __forceinline__ void fsplit(float o, u16& h, u16& l) {
  unsigned u = __builtin_bit_cast(unsigned, o);
  h = (u16)(u >> 16);  // truncate; lo compensates
  float hf = __builtin_bit_cast(float, u & 0xffff0000u);
  l = (u16)(__builtin_bit_cast(unsigned, o - hf) >> 16);
}
// all MFMA operand frags: row = base+(lane&15), 8 ushorts at ko = 32*ks+8*(lane>>4)
__device__ __forceinline__ short8 ldfrag(const u16* p, int row, int ko) {
  return *(const short8*)&p[row * PST + ko];
}

// ---- depthwise 3x3 conv: one run = 8 tokens (n=nb..nb+7) at one feature dcol --
__device__ __forceinline__ void conv_run(const float* __restrict__ pl,
                                         const float* __restrict__ w9, int cd,
                                         int r, float o[8], int& nb,
                                         int& dcol) {
  int lr = r >> 5, w0 = r & 31;
  int h = cd * 16 + lr;
  float rv[3][10];
#pragma unroll
  for (int dy = 0; dy < 3; ++dy) {
    int hy = h + dy - 1;
    bool hv = (hy >= 0) && (hy < 256);
#pragma unroll
    for (int j = 0; j < 10; ++j) rv[dy][j] = 0.f;
    if (hv) {
      const float* rp = pl + hy * 256;
      const float4* rp4 = (const float4*)(rp + w0 * 8);
      float4 a = rp4[0], b4 = rp4[1];
      rv[dy][1] = a.x;  rv[dy][2] = a.y;  rv[dy][3] = a.z;  rv[dy][4] = a.w;
      rv[dy][5] = b4.x; rv[dy][6] = b4.y; rv[dy][7] = b4.z; rv[dy][8] = b4.w;
      rv[dy][0] = (w0 > 0) ? rp[w0 * 8 - 1] : 0.f;
      rv[dy][9] = (w0 < 31) ? rp[w0 * 8 + 8] : 0.f;
    }
  }
  nb = (lr & 7) * 8;
  dcol = ((lr >> 3) << 5) + w0;
#pragma unroll
  for (int i = 0; i < 8; ++i) {
    o[i] = fmaf(w9[0], rv[0][i], fmaf(w9[1], rv[0][i + 1], fmaf(w9[2], rv[0][i + 2],
            fmaf(w9[3], rv[1][i], fmaf(w9[4], rv[1][i + 1], fmaf(w9[5], rv[1][i + 2],
            fmaf(w9[6], rv[2][i], fmaf(w9[7], rv[2][i + 1], w9[8] * rv[2][i + 2]))))))));
  }
}

// stage Q/K chunk as hi/lo planes [64 n][PST d]  (scalar b16 writes, ~4-way ok)
__device__ __forceinline__ void stage_nk(const float* __restrict__ pl,
                                         const float* __restrict__ w9,
                                         u16* __restrict__ ph,
                                         u16* __restrict__ plo, int cd, int t) {
#pragma unroll
  for (int rr = 0; rr < 2; ++rr) {
    float o[8]; int nb, dcol;
    conv_run(pl, w9, cd, t + rr * 256, o, nb, dcol);
#pragma unroll
    for (int i = 0; i < 8; ++i) {
      u16 h, l;
      fsplit(o[i], h, l);
      ph[(nb + i) * PST + dcol] = h;
      plo[(nb + i) * PST + dcol] = l;
    }
  }
}

// stage V chunk TRANSPOSED [64 d][PST n]: 8 consecutive n -> packed b128 writes
__device__ __forceinline__ void stage_vt(const float* __restrict__ pl,
                                         const float* __restrict__ w9,
                                         u16* __restrict__ ph,
                                         u16* __restrict__ plo, int cd, int t) {
#pragma unroll
  for (int rr = 0; rr < 2; ++rr) {
    float o[8]; int nb, dcol;
    conv_run(pl, w9, cd, t + rr * 256, o, nb, dcol);
    short8 hv, lv;
#pragma unroll
    for (int i = 0; i < 8; ++i) {
      u16 h, l;
      fsplit(o[i], h, l);
      hv[i] = (short)h;
      lv[i] = (short)l;
    }
    *(short8*)&ph[dcol * PST + nb] = hv;
    *(short8*)&plo[dcol * PST + nb] = lv;
  }
}

// ---------------- K2: MFMA attention, conv fused in staging ----------------
// Per (b,ch): 16 chunks of d=64. QK^T: S(64x64) += Q_chunk . K_chunk^T via
// mfma_f32_16x16x32_bf16 with hi/lo split (3 products, ~fp32 accuracy).
// Norm rescale commutes: S = (q.k) * invq * invk * temp, applied pre-softmax.
// Wave wid owns S rows 16*wid..+15 (A rows); all 4 col-blocks as B frags.
__global__ __launch_bounds__(256) void k_attn(
    const float* __restrict__ qkv0, const float* __restrict__ wdw,
    const float* __restrict__ temperature, float* __restrict__ out) {
  __shared__ u16 SAh[64 * PST], SAl[64 * PST];  // Q planes, then P planes
  __shared__ u16 SBh[64 * PST], SBl[64 * PST];  // K planes, then V^T planes
  __shared__ float red[64 * 8];
  __shared__ float invn[128];

  const int t = threadIdx.x;
  const int b = blockIdx.x >> 6, ch = blockIdx.x & 63;
  const float* qpl = qkv0 + (((size_t)b * 192 + ch) << 16);
  const float* kpl = qkv0 + (((size_t)b * 192 + 64 + ch) << 16);
  const float* vpl = qkv0 + (((size_t)b * 192 + 128 + ch) << 16);
  float wq[9], wk[9], wv[9];
#pragma unroll
  for (int i = 0; i < 9; ++i) {
    wq[i] = wdw[ch * 9 + i];
    wk[i] = wdw[(64 + ch) * 9 + i];
    wv[i] = wdw[(128 + ch) * 9 + i];
  }
  const float tscale = temperature[ch >> 3];

  const int wid = t >> 6;        // wave 0..3: S rows 16*wid..+15
  const int g = (t >> 4) & 3;    // lane>>4 within wave
  const int r16 = t & 15;        // lane&15

  f4 acc[4];
#pragma unroll
  for (int cb = 0; cb < 4; ++cb)
#pragma unroll
    for (int e = 0; e < 4; ++e) acc[cb][e] = 0.f;
  float sqQ = 0.f, sqK = 0.f;

  for (int cd = 0; cd < 16; ++cd) {
    stage_nk(qpl, wq, SAh, SAl, cd, t);
    stage_nk(kpl, wk, SBh, SBl, cd, t);
    __syncthreads();
    {  // sumsq on reconstructed (hi+lo) values: row n=t>>2, 16 cols
      const int n = t >> 2, c0 = (t & 3) << 4;
#pragma unroll
      for (int h2 = 0; h2 < 2; ++h2) {
        short8 qh = *(const short8*)&SAh[n * PST + c0 + 8 * h2];
        short8 ql = *(const short8*)&SAl[n * PST + c0 + 8 * h2];
        short8 kh = *(const short8*)&SBh[n * PST + c0 + 8 * h2];
        short8 kl = *(const short8*)&SBl[n * PST + c0 + 8 * h2];
#pragma unroll
        for (int e = 0; e < 8; ++e) {
          float qv = tof((u16)qh[e]) + tof((u16)ql[e]);
          float kv = tof((u16)kh[e]) + tof((u16)kl[e]);
          sqQ = fmaf(qv, qv, sqQ);
          sqK = fmaf(kv, kv, sqK);
        }
      }
    }
#pragma unroll
    for (int ks = 0; ks < 2; ++ks) {
      const int ko = ks * 32 + g * 8;
      short8 ah = ldfrag(SAh, wid * 16 + r16, ko);
      short8 al = ldfrag(SAl, wid * 16 + r16, ko);
#pragma unroll
      for (int cb = 0; cb < 4; ++cb) {
        short8 bh = ldfrag(SBh, cb * 16 + r16, ko);
        short8 bl = ldfrag(SBl, cb * 16 + r16, ko);
        acc[cb] = __builtin_amdgcn_mfma_f32_16x16x32_bf16(ah, bh, acc[cb], 0, 0, 0);
        acc[cb] = __builtin_amdgcn_mfma_f32_16x16x32_bf16(ah, bl, acc[cb], 0, 0, 0);
        acc[cb] = __builtin_amdgcn_mfma_f32_16x16x32_bf16(al, bh, acc[cb], 0, 0, 0);
      }
    }
    __syncthreads();
  }

  // reduce sumsq -> 1/max(||.||, 1e-12)
  red[(t >> 2) * 8 + (t & 3)] = sqQ;
  red[(t >> 2) * 8 + 4 + (t & 3)] = sqK;
  __syncthreads();
  if (t < 128) {
    int n = t & 63;
    int o = (t >> 6) * 4;
    float s = red[n * 8 + o] + red[n * 8 + o + 1] + red[n * 8 + o + 2] +
              red[n * 8 + o + 3];
    invn[(t >> 6) * 64 + n] = 1.f / fmaxf(sqrtf(s), 1e-12f);
  }
  __syncthreads();

  // scale + softmax. C/D layout: row n = 16*wid+4*g+r, col m = 16*cb+r16.
  float iqv[4], ikv[4];
#pragma unroll
  for (int r = 0; r < 4; ++r) iqv[r] = invn[wid * 16 + g * 4 + r];
#pragma unroll
  for (int cb = 0; cb < 4; ++cb) ikv[cb] = invn[64 + cb * 16 + r16];
  float pr[4][4];  // [r][cb]
#pragma unroll
  for (int r = 0; r < 4; ++r) {
    float sv[4];
#pragma unroll
    for (int cb = 0; cb < 4; ++cb)
      sv[cb] = acc[cb][r] * iqv[r] * ikv[cb] * tscale;
    float mx = fmaxf(fmaxf(sv[0], sv[1]), fmaxf(sv[2], sv[3]));
#pragma unroll
    for (int off = 1; off < 16; off <<= 1) mx = fmaxf(mx, __shfl_xor(mx, off));
    float ss = 0.f;
#pragma unroll
    for (int cb = 0; cb < 4; ++cb) {
      sv[cb] = __expf(sv[cb] - mx);
      ss += sv[cb];
    }
#pragma unroll
    for (int off = 1; off < 16; off <<= 1) ss += __shfl_xor(ss, off);
    float rs = 1.f / ss;
#pragma unroll
    for (int cb = 0; cb < 4; ++cb) pr[r][cb] = sv[cb] * rs;
  }

  // restage P into SA planes [64 n][PST m] (Q fully consumed)
#pragma unroll
  for (int r = 0; r < 4; ++r)
#pragma unroll
    for (int cb = 0; cb < 4; ++cb) {
      u16 h, l;
      fsplit(pr[r][cb], h, l);
      int n = wid * 16 + g * 4 + r, m = cb * 16 + r16;
      SAh[n * PST + m] = h;
      SAl[n * PST + m] = l;
    }
  __syncthreads();

  // P A-frags fixed across chunks: row = 16*wid + r16, k = m
  short8 pah[2], pal[2];
#pragma unroll
  for (int ks = 0; ks < 2; ++ks) {
    pah[ks] = ldfrag(SAh, wid * 16 + r16, ks * 32 + g * 8);
    pal[ks] = ldfrag(SAl, wid * 16 + r16, ks * 32 + g * 8);
  }

  // PV: per chunk O(64n x 64d) = P(64x64) . V(64m x 64d); B from V^T planes
  size_t obase = ((size_t)b * 64 + ch) << 16;
  for (int cd = 0; cd < 16; ++cd) {
    stage_vt(vpl, wv, SBh, SBl, cd, t);
    __syncthreads();
    f4 po[4];
#pragma unroll
    for (int cb = 0; cb < 4; ++cb)
#pragma unroll
      for (int e = 0; e < 4; ++e) po[cb][e] = 0.f;
#pragma unroll
    for (int ks = 0; ks < 2; ++ks) {
      const int ko = ks * 32 + g * 8;
#pragma unroll
      for (int cb = 0; cb < 4; ++cb) {
        short8 bh = ldfrag(SBh, cb * 16 + r16, ko);
        short8 bl = ldfrag(SBl, cb * 16 + r16, ko);
        po[cb] = __builtin_amdgcn_mfma_f32_16x16x32_bf16(pah[ks], bh, po[cb], 0, 0, 0);
        po[cb] = __builtin_amdgcn_mfma_f32_16x16x32_bf16(pah[ks], bl, po[cb], 0, 0, 0);
        po[cb] = __builtin_amdgcn_mfma_f32_16x16x32_bf16(pal[ks], bh, po[cb], 0, 0, 0);
      }
    }
#pragma unroll
    for (int cb = 0; cb < 4; ++cb)
#pragma unroll
      for (int r = 0; r < 4; ++r) {
        int n = wid * 16 + g * 4 + r;
        int d = cd * 64 + cb * 16 + r16;
        int hh = ((d >> 5) << 3) + (n >> 3);
        int ww = ((d & 31) << 3) + (n & 7);
        out[obase + hh * 256 + ww] = po[cb][r];
      }
    __syncthreads();
  }
}

extern "C" void kernel_launch(void* const* d_in, const int* in_sizes, int n_in,
                              void* d_out, int out_size, void* d_ws,
                              size_t ws_size, hipStream_t stream) {
  const float* x = (const float*)d_in[0];
  const float* wqkv = (const float*)d_in[1];
  const float* wdw = (const float*)d_in[2];
  const float* wproj = (const float*)d_in[3];
  const float* temp = (const float*)d_in[4];
  float* out = (float*)d_out;
  float* qkv0 = (float*)d_ws;  // 8*192*65536*4 = 402,653,184 bytes

  k_pw<192><<<8192, 256, 0, stream>>>(x, wqkv, qkv0);
  k_attn<<<512, 256, 0, stream>>>(qkv0, wdw, temp, out);
  k_pw<64><<<8192, 256, 0, stream>>>(out, wproj, out);
}